// Round 1
// baseline (489.280 us; speedup 1.0000x reference)
//
#include <hip/hip_runtime.h>
#include <math.h>

// ---------------------------------------------------------------------------
// K1: fused maxpool3x3(stride1,pad1) + blurpool(4x4 [1,3,3,1]^2/64, stride3,
//     reflect pad (1,2)) : x (plane,192,192) -> xtem (plane,64,64)
// Block = one (plane, 8-output-row chunk). LDS-stage x rows, then mp rows.
// ---------------------------------------------------------------------------
__global__ __launch_bounds__(256) void k1_pool(const float* __restrict__ x,
                                               float* __restrict__ xtem) {
    const int plane = blockIdx.y;          // b*64+c, 0..1023
    const int chunk = blockIdx.x;          // 0..7
    const int i0 = chunk * 8;
    const int R0 = max(0, 3 * i0 - 2), R1 = min(191, 3 * i0 + 24);
    const int M0 = max(0, 3 * i0 - 1), M1 = min(191, 3 * i0 + 23);
    const int nxr = R1 - R0 + 1;           // <= 27
    const int nmr = M1 - M0 + 1;           // <= 25

    __shared__ float xs[27 * 192];
    __shared__ float ms[25 * 192];

    const float* xp = x + (size_t)plane * (192 * 192);
    const int nf4 = nxr * 48;
    for (int f = threadIdx.x; f < nf4; f += 256) {
        int r = f / 48, c4 = f - r * 48;
        ((float4*)xs)[r * 48 + c4] =
            ((const float4*)(xp + (size_t)(R0 + r) * 192))[c4];
    }
    __syncthreads();

    // maxpool 3x3 (pad = -inf == clamp)
    const int nm = nmr * 192;
    for (int e = threadIdx.x; e < nm; e += 256) {
        int lm = e / 192, n = e - lm * 192;
        int m = M0 + lm;
        int rlo = max(m - 1, 0) - R0, rhi = min(m + 1, 191) - R0;
        int nlo = max(n - 1, 0), nhi = min(n + 1, 191);
        float mv = -3.4e38f;
        for (int rr = rlo; rr <= rhi; ++rr) {
            const float* row = xs + rr * 192;
            for (int nn = nlo; nn <= nhi; ++nn) mv = fmaxf(mv, row[nn]);
        }
        ms[lm * 192 + n] = mv;
    }
    __syncthreads();

    // blur: x_tem[i,j] = (1/64) sum_{u,v} a[u]a[v] mp[refl(3i+u-1)][refl(3j+v-1)]
    const int j = threadIdx.x & 63;
    const int isub = threadIdx.x >> 6;
    int cols[4];
#pragma unroll
    for (int v = 0; v < 4; ++v) {
        int n = 3 * j + v - 1;
        if (n < 0) n = -n;
        if (n > 191) n = 382 - n;
        cols[v] = n;
    }
#pragma unroll
    for (int s = 0; s < 2; ++s) {
        int i = i0 + isub + 4 * s;
        float acc = 0.f;
#pragma unroll
        for (int u = 0; u < 4; ++u) {
            int m = 3 * i + u - 1;
            if (m < 0) m = -m;
            if (m > 191) m = 382 - m;
            const float* mrow = ms + (m - M0) * 192;
            float au = (u == 0 || u == 3) ? 1.f : 3.f;
            float rs = mrow[cols[0]] + 3.f * mrow[cols[1]] +
                       3.f * mrow[cols[2]] + mrow[cols[3]];
            acc += au * rs;
        }
        xtem[(size_t)plane * 4096 + i * 64 + j] = acc * (1.f / 64.f);
    }
}

// ---------------------------------------------------------------------------
// K2: att = h1 + w1 + h2(diag) + w2(diag) on x_tem, then BN + sigmoid -> gate.
// Derived direct stencils (all zero-padded, bounds exactly the 64x64 tile):
//   h1[i,j] = sum_{p<11,q<3} Wh1[p][q] T[i+p-5][j+q-1]
//   w1[i,j] = sum_{p<3,q<11} Wv1[p][q] T[i+p-1][j+q-5]
//   h2[i,j] = sum_{p<11,q<3} Wh2[p][q] T[i+p-5][j+q+4-p]
//   w2[i,j] = sum_{p<3,q<11} Wv2[p][q] T[i+p-q+4][j+q-5]
// Lane = column j. Slide input row t; w_[d] = T[t][j+d-6]; contribution from
// tap with row-offset dr goes to acc[6-dr] (rolling 13-deep window).
// Block = 256 thr = 4 waves: 2 planes (same c -> scalarizable weights),
// 2 row-strips of 32 each.
// ---------------------------------------------------------------------------
__global__ __launch_bounds__(256) void k2_att(
    const float* __restrict__ xtem,
    const float* __restrict__ wh1g, const float* __restrict__ wv1g,
    const float* __restrict__ wh2g, const float* __restrict__ wv2g,
    const float* __restrict__ gamma, const float* __restrict__ beta,
    const float* __restrict__ mean, const float* __restrict__ var,
    float* __restrict__ gate) {
    const int c = blockIdx.x & 63;           // plane = blockIdx.x + 512*pl
    __shared__ float T[2 * 64 * 80];         // per plane: 64 rows x 80 (cols 6..69 live)

    for (int e = threadIdx.x; e < 2 * 64 * 80; e += 256) T[e] = 0.f;
    __syncthreads();
    for (int e = threadIdx.x; e < 2 * 4096; e += 256) {
        int pl = e >> 12, e2 = e & 4095;
        T[pl * 5120 + (e2 >> 6) * 80 + 6 + (e2 & 63)] =
            xtem[((size_t)(blockIdx.x + 512 * pl)) * 4096 + e2];
    }

    float Wh1[33], Wv1[33], Wh2[33], Wv2[33];
#pragma unroll
    for (int k = 0; k < 33; ++k) {
        Wh1[k] = wh1g[c * 33 + k];
        Wv1[k] = wv1g[c * 33 + k];
        Wh2[k] = wh2g[c * 33 + k];
        Wv2[k] = wv2g[c * 33 + k];
    }
    const float inv = gamma[c] * rsqrtf(var[c] + 1e-5f);
    const float bias = beta[c] - mean[c] * inv;
    __syncthreads();

    const int wid = threadIdx.x >> 6;
    const int j = threadIdx.x & 63;
    const int pl = wid >> 1;
    const int ib = (wid & 1) * 32;
    const float* Tb = T + pl * 5120;
    float* gp = gate + (size_t)(blockIdx.x + 512 * pl) * 4096;

    float acc[13];
#pragma unroll
    for (int k = 0; k < 13; ++k) acc[k] = 0.f;

    for (int t = ib - 6; t < ib + 38; ++t) {
        if (t >= 0 && t < 64) {
            float w_[13];
#pragma unroll
            for (int d = 0; d < 13; ++d) w_[d] = Tb[t * 80 + j + d];
            // h1 (dr=p-5, col d=q+5) and h2 (dr=p-5, col d=q+10-p) share acc[11-p]
#pragma unroll
            for (int p = 0; p < 11; ++p) {
                acc[11 - p] += Wh1[p * 3 + 0] * w_[5] + Wh1[p * 3 + 1] * w_[6] +
                               Wh1[p * 3 + 2] * w_[7] +
                               Wh2[p * 3 + 0] * w_[10 - p] +
                               Wh2[p * 3 + 1] * w_[11 - p] +
                               Wh2[p * 3 + 2] * w_[12 - p];
            }
            // w1 (dr=p-1 -> acc[7-p], col d=q+1); w2 (dr=p-q+4 -> acc[2-p+q], col d=q+1)
#pragma unroll
            for (int p = 0; p < 3; ++p) {
#pragma unroll
                for (int q = 0; q < 11; ++q) {
                    acc[7 - p] += Wv1[p * 11 + q] * w_[q + 1];
                    acc[2 - p + q] += Wv2[p * 11 + q] * w_[q + 1];
                }
            }
        }
        int i = t - 6;  // this output row is now complete
        if (i >= ib) {
            float z = acc[0] * inv + bias;
            gp[i * 64 + j] = 1.f / (1.f + __expf(-z));
        }
#pragma unroll
        for (int k = 0; k < 12; ++k) acc[k] = acc[k + 1];
        acc[12] = 0.f;
    }
}

// ---------------------------------------------------------------------------
// K3: out = x * gate[i/3, j/3], float4 streaming. 4 consecutive j span exactly
// 2 gate cells (g0, g0+1).
// ---------------------------------------------------------------------------
__global__ __launch_bounds__(256) void k3_mul(const float* __restrict__ x,
                                              const float* __restrict__ gate,
                                              float* __restrict__ out) {
    int idx = blockIdx.x * 256 + threadIdx.x;      // float4 index, < 9437184
    int j4 = idx % 48;
    int rest = idx / 48;
    int i = rest % 192;
    int plane = rest / 192;
    float4 xv = ((const float4*)x)[idx];
    const float* gp = gate + (size_t)plane * 4096 + (i / 3) * 64;
    int jj = 4 * j4;
    int g0 = jj / 3;
    int r = jj - 3 * g0;
    float ga = gp[g0], gb = gp[g0 + 1];
    float4 o;
    o.x = xv.x * ga;
    o.y = xv.y * (r == 2 ? gb : ga);
    o.z = xv.z * (r == 0 ? ga : gb);
    o.w = xv.w * gb;
    ((float4*)out)[idx] = o;
}

extern "C" void kernel_launch(void* const* d_in, const int* in_sizes, int n_in,
                              void* d_out, int out_size, void* d_ws, size_t ws_size,
                              hipStream_t stream) {
    const float* x     = (const float*)d_in[0];
    const float* wh1   = (const float*)d_in[1];
    const float* wv1   = (const float*)d_in[2];
    const float* wh2   = (const float*)d_in[3];
    const float* wv2   = (const float*)d_in[4];
    const float* gamma = (const float*)d_in[5];
    const float* beta  = (const float*)d_in[6];
    const float* mean  = (const float*)d_in[7];
    const float* var   = (const float*)d_in[8];
    float* out  = (float*)d_out;
    float* xtem = (float*)d_ws;                 // 1024*4096 floats = 16 MB
    float* gate = xtem + (size_t)1024 * 4096;   // 16 MB

    k1_pool<<<dim3(8, 1024), 256, 0, stream>>>(x, xtem);
    k2_att<<<512, 256, 0, stream>>>(xtem, wh1, wv1, wh2, wv2,
                                    gamma, beta, mean, var, gate);
    k3_mul<<<36864, 256, 0, stream>>>(x, gate, out);
}

// Round 2
// 387.061 us; speedup vs baseline: 1.2641x; 1.2641x over previous
//
#include <hip/hip_runtime.h>
#include <math.h>

// ---------------------------------------------------------------------------
// K1: fused maxpool3x3(stride1,pad1) + blurpool(4x4 [1,3,3,1]^2/64, stride3,
//     reflect pad (1,2)) : x (plane,192,192) -> xtem (plane,64,64)
// Separable formulation:
//   vm[m][n]  = max over rows m-1..m+1 (clamped) of x[.][n]
//   hm(m,c)   = max over cols c-1..c+1 (clamped) of vm[m][.]   (= maxpool)
//   cb[m][j]  = sum_v a[v] * hm(m, refl(3j+v-1))               (col blur)
//   out[i][j] = (1/64) sum_u a[u] * cb[refl(3i+u-1)][j]        (row blur)
// Block = one (plane, 8-output-row chunk).
// ---------------------------------------------------------------------------
__global__ __launch_bounds__(256) void k1_pool(const float* __restrict__ x,
                                               float* __restrict__ xtem) {
    const int plane = blockIdx.y;          // 0..1023
    const int i0 = blockIdx.x * 8;         // chunk of 8 output rows
    const int M0 = max(0, 3 * i0 - 1), M1 = min(191, 3 * i0 + 23);
    const int R0 = max(0, M0 - 1), R1 = min(191, M1 + 1);
    const int nxr = R1 - R0 + 1;           // <= 27
    const int nmr = M1 - M0 + 1;           // <= 25

    __shared__ float xs[27 * 192];
    __shared__ float vm[25 * 192];
    float* cb = xs;                        // reuse xs after vm is built

    // stage x rows R0..R1
    const float* xp = x + (size_t)plane * (192 * 192);
    const int nf4 = nxr * 48;
    for (int f = threadIdx.x; f < nf4; f += 256) {
        int r = f / 48, c4 = f - r * 48;
        ((float4*)xs)[r * 48 + c4] =
            ((const float4*)(xp + (size_t)(R0 + r) * 192))[c4];
    }
    __syncthreads();

    // vertical 3-max: one column per thread (threads 192..255 idle)
    if (threadIdx.x < 192) {
        const int n = threadIdx.x;
        for (int lm = 0; lm < nmr; ++lm) {
            int m = M0 + lm;
            int rlo = max(m - 1, 0) - R0, rhi = min(m + 1, 191) - R0;
            float mv = xs[rlo * 192 + n];
            for (int r = rlo + 1; r <= rhi; ++r)
                mv = fmaxf(mv, xs[r * 192 + n]);
            vm[lm * 192 + n] = mv;
        }
    }
    __syncthreads();

    // horizontal 3-max + column blur -> cb[lm][j]  (nmr x 64)
    {
        const int j = threadIdx.x & 63;
        const int r0 = threadIdx.x >> 6;   // 0..3
        int cc[4], cm[4], cp[4];
#pragma unroll
        for (int v = 0; v < 4; ++v) {
            int c = 3 * j + v - 1;
            if (c < 0) c = -c;             // reflect (only j=0,v=0)
            cc[v] = c;
            cm[v] = max(c - 1, 0);
            cp[v] = min(c + 1, 191);
        }
        for (int lm = r0; lm < nmr; lm += 4) {
            const float* vr = vm + lm * 192;
            float s = 0.f;
#pragma unroll
            for (int v = 0; v < 4; ++v) {
                float h = fmaxf(fmaxf(vr[cm[v]], vr[cc[v]]), vr[cp[v]]);
                s += (v == 0 || v == 3) ? h : 3.f * h;
            }
            cb[lm * 64 + j] = s;
        }
    }
    __syncthreads();

    // row blur -> output
    {
        const int j = threadIdx.x & 63;
        const int isub = threadIdx.x >> 6;
#pragma unroll
        for (int s = 0; s < 2; ++s) {
            int i = i0 + isub + 4 * s;
            float acc = 0.f;
#pragma unroll
            for (int u = 0; u < 4; ++u) {
                int m = 3 * i + u - 1;
                if (m < 0) m = -m;         // reflect (only i=0,u=0)
                float au = (u == 0 || u == 3) ? 1.f : 3.f;
                acc += au * cb[(m - M0) * 64 + j];
            }
            xtem[(size_t)plane * 4096 + i * 64 + j] = acc * (1.f / 64.f);
        }
    }
}

// ---------------------------------------------------------------------------
// K2: att = h1 + w1 + h2(diag) + w2(diag) on x_tem, then BN + sigmoid -> gate.
// Direct stencils (zero-padded, bounded by the 64x64 tile):
//   h1[i,j] = sum_{p<11,q<3} Wh1[p][q] T[i+p-5][j+q-1]
//   h2[i,j] = sum_{p<11,q<3} Wh2[p][q] T[i+p-5][j+q+4-p]
//   w1[i,j] = sum_{p<3,q<11} Wv1[p][q] T[i+p-1][j+q-5]
//   w2[i,j] = sum_{p<3,q<11} Wv2[p][q] T[i+p-q+4][j+q-5]
// TWO PASSES to keep live weights at 66 (no spills): pass H (Wh1,Wh2) buffers
// partial rows in LDS att[]; pass V (Wv1,Wv2) adds + BN + sigmoid.
// Rolling 13-deep accumulator: processing input row t, a tap with row offset
// dr = t - i lands in acc[6 - dr]; output i = t-6 reads acc[0], then shift.
// Block = 1 plane, 4 waves = 4 strips of 16 rows; lane = column j.
// ---------------------------------------------------------------------------
__global__ __launch_bounds__(256) void k2_att(
    const float* __restrict__ xtem,
    const float* __restrict__ wh1g, const float* __restrict__ wv1g,
    const float* __restrict__ wh2g, const float* __restrict__ wv2g,
    const float* __restrict__ gamma, const float* __restrict__ beta,
    const float* __restrict__ mean, const float* __restrict__ var,
    float* __restrict__ gate) {
    const int plane = blockIdx.x;          // 0..1023
    const int c = plane & 63;
    __shared__ float T[64 * 80];           // cols 6..69 live, rest zero
    __shared__ float att[64 * 64];

    for (int e = threadIdx.x; e < 64 * 80; e += 256) T[e] = 0.f;
    __syncthreads();
    for (int e = threadIdx.x; e < 4096; e += 256)
        T[(e >> 6) * 80 + 6 + (e & 63)] = xtem[(size_t)plane * 4096 + e];

    const float inv = gamma[c] * rsqrtf(var[c] + 1e-5f);
    const float bias = beta[c] - mean[c] * inv;
    __syncthreads();

    const int j = threadIdx.x & 63;
    const int ib = (threadIdx.x >> 6) * 16;   // strip base row

    float Wa[33], Wb[33];
    float acc[13];

    // ---- Pass H: h1 + h2 ----
#pragma unroll
    for (int k = 0; k < 33; ++k) {
        Wa[k] = wh1g[c * 33 + k];
        Wb[k] = wh2g[c * 33 + k];
    }
#pragma unroll
    for (int k = 0; k < 13; ++k) acc[k] = 0.f;
    for (int t = ib - 6; t <= ib + 21; ++t) {
        if (t >= 0 && t < 64) {
            float w_[13];
#pragma unroll
            for (int d = 0; d < 13; ++d) w_[d] = T[t * 80 + j + d];
#pragma unroll
            for (int p = 0; p < 11; ++p) {
                acc[11 - p] += Wa[p * 3 + 0] * w_[5] + Wa[p * 3 + 1] * w_[6] +
                               Wa[p * 3 + 2] * w_[7] +
                               Wb[p * 3 + 0] * w_[10 - p] +
                               Wb[p * 3 + 1] * w_[11 - p] +
                               Wb[p * 3 + 2] * w_[12 - p];
            }
        }
        int i = t - 6;
        if (i >= ib) att[i * 64 + j] = acc[0];
#pragma unroll
        for (int k = 0; k < 12; ++k) acc[k] = acc[k + 1];
        acc[12] = 0.f;
    }

    // ---- Pass V: w1 + w2, then BN + sigmoid ----
#pragma unroll
    for (int k = 0; k < 33; ++k) {
        Wa[k] = wv1g[c * 33 + k];
        Wb[k] = wv2g[c * 33 + k];
    }
#pragma unroll
    for (int k = 0; k < 13; ++k) acc[k] = 0.f;
    float* gp = gate + (size_t)plane * 4096;
    for (int t = ib - 6; t <= ib + 21; ++t) {
        if (t >= 0 && t < 64) {
            float w_[13];
#pragma unroll
            for (int d = 0; d < 13; ++d) w_[d] = T[t * 80 + j + d];
#pragma unroll
            for (int p = 0; p < 3; ++p) {
#pragma unroll
                for (int q = 0; q < 11; ++q) {
                    acc[7 - p] += Wa[p * 11 + q] * w_[q + 1];
                    acc[2 - p + q] += Wb[p * 11 + q] * w_[q + 1];
                }
            }
        }
        int i = t - 6;
        if (i >= ib) {
            float z = (att[i * 64 + j] + acc[0]) * inv + bias;
            gp[i * 64 + j] = 1.f / (1.f + __expf(-z));
        }
#pragma unroll
        for (int k = 0; k < 12; ++k) acc[k] = acc[k + 1];
        acc[12] = 0.f;
    }
}

// ---------------------------------------------------------------------------
// K3: out = x * gate[i/3, j/3], float4 streaming. 4 consecutive j span exactly
// 2 gate cells (g0, g0+1).
// ---------------------------------------------------------------------------
__global__ __launch_bounds__(256) void k3_mul(const float* __restrict__ x,
                                              const float* __restrict__ gate,
                                              float* __restrict__ out) {
    int idx = blockIdx.x * 256 + threadIdx.x;      // float4 index, < 9437184
    int j4 = idx % 48;
    int rest = idx / 48;
    int i = rest % 192;
    int plane = rest / 192;
    float4 xv = ((const float4*)x)[idx];
    const float* gp = gate + (size_t)plane * 4096 + (i / 3) * 64;
    int jj = 4 * j4;
    int g0 = jj / 3;
    int r = jj - 3 * g0;
    float ga = gp[g0], gb = gp[g0 + 1];
    float4 o;
    o.x = xv.x * ga;
    o.y = xv.y * (r == 2 ? gb : ga);
    o.z = xv.z * (r == 0 ? ga : gb);
    o.w = xv.w * gb;
    ((float4*)out)[idx] = o;
}

extern "C" void kernel_launch(void* const* d_in, const int* in_sizes, int n_in,
                              void* d_out, int out_size, void* d_ws, size_t ws_size,
                              hipStream_t stream) {
    const float* x     = (const float*)d_in[0];
    const float* wh1   = (const float*)d_in[1];
    const float* wv1   = (const float*)d_in[2];
    const float* wh2   = (const float*)d_in[3];
    const float* wv2   = (const float*)d_in[4];
    const float* gamma = (const float*)d_in[5];
    const float* beta  = (const float*)d_in[6];
    const float* mean  = (const float*)d_in[7];
    const float* var   = (const float*)d_in[8];
    float* out  = (float*)d_out;
    float* xtem = (float*)d_ws;                 // 1024*4096 floats = 16 MB
    float* gate = xtem + (size_t)1024 * 4096;   // 16 MB

    k1_pool<<<dim3(8, 1024), 256, 0, stream>>>(x, xtem);
    k2_att<<<1024, 256, 0, stream>>>(xtem, wh1, wv1, wh2, wv2,
                                     gamma, beta, mean, var, gate);
    k3_mul<<<36864, 256, 0, stream>>>(x, gate, out);
}